// Round 1
// baseline (526.808 us; speedup 1.0000x reference)
//
#include <hip/hip_runtime.h>
#include <hip/hip_bf16.h>
#include <math.h>

// Causal linear attention, chunkwise. Shapes fixed by the reference:
// [N=4, L=4096, H=16, D=64], M=64, CHUNK=128, G=32.
static constexpr int Nn = 4, Ll = 4096, Hh = 16, Dd = 64, Mm = 64, Cc = 128, Gg = 32;
static constexpr int ROWS = Hh * Dd;  // 1024 floats: l-stride in [N,L,H,D]
#define EPS_ 1e-6f

__device__ __forceinline__ float phi(float x) {
    // elu(x)+1 = x+1 (x>0) else exp(x)
    return x > 0.0f ? x + 1.0f : __expf(x);
}

// ---------------------------------------------------------------------------
// Kernel 1: per-chunk KV state kv[d][m] = sum_c phi(k[c][d]) * v[c][m]
//           and ksum[d] = sum_c phi(k[c][d]).   One block per (n,g,h).
// ---------------------------------------------------------------------------
__global__ __launch_bounds__(256) void kv_state_kernel(
    const float* __restrict__ keys, const float* __restrict__ values,
    float* __restrict__ kvbuf, float* __restrict__ ksumbuf)
{
    __shared__ float kS[Cc * 64];  // 32 KB, phi(k) [c][d]
    __shared__ float vS[Cc * 64];  // 32 KB, v      [c][m]

    const int b = blockIdx.x;
    const int h = b % Hh;
    const int g = (b / Hh) % Gg;
    const int n = b / (Hh * Gg);
    const int tid = threadIdx.x;

    const size_t inbase = ((size_t)(n * Ll + g * Cc) * Hh + h) * Dd;

    for (int i = tid; i < Cc * 16; i += 256) {
        const int r = i >> 4, c4 = (i & 15) * 4;
        float4 kk = *(const float4*)(keys   + inbase + (size_t)r * ROWS + c4);
        float4 vv = *(const float4*)(values + inbase + (size_t)r * ROWS + c4);
        float4 kp = make_float4(phi(kk.x), phi(kk.y), phi(kk.z), phi(kk.w));
        *(float4*)(kS + r * 64 + c4) = kp;
        *(float4*)(vS + r * 64 + c4) = vv;
    }
    __syncthreads();

    const int tx = tid & 15, ty = tid >> 4;
    const int d0 = ty * 4, m0 = tx * 4;
    float acc[4][4] = {};
    for (int c = 0; c < Cc; ++c) {
        float4 k4 = *(const float4*)(kS + c * 64 + d0);
        float4 v4 = *(const float4*)(vS + c * 64 + m0);
        const float ks4[4] = {k4.x, k4.y, k4.z, k4.w};
        const float vs4[4] = {v4.x, v4.y, v4.z, v4.w};
        #pragma unroll
        for (int a = 0; a < 4; ++a) {
            #pragma unroll
            for (int e = 0; e < 4; ++e) acc[a][e] += ks4[a] * vs4[e];
        }
    }

    float* kvout = kvbuf + ((size_t)((n * Gg + g) * Hh + h)) * (Dd * Mm);
    #pragma unroll
    for (int a = 0; a < 4; ++a) {
        float4 o = make_float4(acc[a][0], acc[a][1], acc[a][2], acc[a][3]);
        *(float4*)(kvout + (d0 + a) * 64 + m0) = o;
    }

    if (tid < 64) {
        float s = 0.f;
        for (int c = 0; c < Cc; ++c) s += kS[c * 64 + tid];
        ksumbuf[((size_t)((n * Gg + g) * Hh + h)) * 64 + tid] = s;
    }
}

// ---------------------------------------------------------------------------
// Kernel 2: in-place EXCLUSIVE prefix over g for kvbuf and ksumbuf.
// One thread per (n,h,d*m) series (coalesced over dm at each g).
// ---------------------------------------------------------------------------
__global__ __launch_bounds__(256) void prefix_kernel(
    float* __restrict__ kvbuf, float* __restrict__ ksumbuf)
{
    const int t = blockIdx.x * 256 + threadIdx.x;
    const int NKV = Nn * Hh * Dd * Mm;  // 262144
    if (t < NKV) {
        const int nh = t >> 12, dm = t & 4095;
        const int n = nh >> 4, h = nh & 15;
        float run = 0.f;
        for (int g = 0; g < Gg; ++g) {
            const size_t idx = ((size_t)((n * Gg + g) * Hh + h)) * 4096 + dm;
            const float v = kvbuf[idx];
            kvbuf[idx] = run;
            run += v;
        }
    } else {
        const int t2 = t - NKV;
        if (t2 < Nn * Hh * Dd) {
            const int nh = t2 >> 6, d = t2 & 63;
            const int n = nh >> 4, h = nh & 15;
            float run = 0.f;
            for (int g = 0; g < Gg; ++g) {
                const size_t idx = ((size_t)((n * Gg + g) * Hh + h)) * 64 + d;
                const float v = ksumbuf[idx];
                ksumbuf[idx] = run;
                run += v;
            }
        }
    }
}

// ---------------------------------------------------------------------------
// Kernel 3: out tile. One block per (n,g,h, row-tile of 32).
//   scores  s[c][j] = phi(q[c]) . phi(k[j])   (causal masked, j,c chunk-local)
//   z[c]    = eps + q.kpre + rowsum(masked scores)
//   out     = ( q.kv_prev + s.v ) / z
// k is XOR-swizzled in LDS (float4 granules) to avoid stride-64 bank conflicts.
// ---------------------------------------------------------------------------
__global__ __launch_bounds__(256) void out_kernel(
    const float* __restrict__ queries,
    const float* __restrict__ keys,
    const float* __restrict__ values,
    const float* __restrict__ kvbuf,
    const float* __restrict__ ksumbuf,
    float* __restrict__ out)
{
    __shared__ float bufA[Cc * 64];   // 32 KB: swizzled phi(k) -> kv_prev -> v
    __shared__ float qS[32 * 68];     // phi(q) tile, padded stride 68
    __shared__ float sS[32 * 132];    // scores, padded stride 132
    __shared__ float zS[32];
    __shared__ float kpS[64];

    const int b  = blockIdx.x;
    const int rt = b & 3;
    const int h  = (b >> 2) & 15;
    const int g  = (b >> 6) & 31;
    const int n  = b >> 11;
    const int tid = threadIdx.x;
    const int tx = tid & 15, ty = tid >> 4;
    const int nk = (rt + 1) * 32;  // causal: k/v rows needed by this row tile

    const size_t chunkbase = ((size_t)(n * Ll + g * Cc) * Hh + h) * Dd;
    const size_t stateoff  = (size_t)((n * Gg + g) * Hh + h);

    // ---- stage phi(k) (swizzled), phi(q) tile, kpre ----
    for (int i = tid; i < nk * 16; i += 256) {
        const int j = i >> 4, cg = i & 15;
        float4 kk = *(const float4*)(keys + chunkbase + (size_t)j * ROWS + cg * 4);
        float4 kp = make_float4(phi(kk.x), phi(kk.y), phi(kk.z), phi(kk.w));
        *(float4*)(bufA + j * 64 + ((cg ^ (j & 15)) << 2)) = kp;
    }
    for (int i = tid; i < 512; i += 256) {
        const int c = i >> 4, cg = i & 15;
        float4 qq = *(const float4*)(queries + chunkbase +
                                     (size_t)(rt * 32 + c) * ROWS + cg * 4);
        float4 qp = make_float4(phi(qq.x), phi(qq.y), phi(qq.z), phi(qq.w));
        *(float4*)(qS + c * 68 + cg * 4) = qp;
    }
    if (tid < 16)
        *(float4*)(kpS + tid * 4) =
            *(const float4*)(ksumbuf + stateoff * 64 + tid * 4);
    __syncthreads();

    // ---- scores: each thread owns rows c0,c0+1 and columns j = tx (mod 16) ----
    const int c0 = ty * 2;
    const int cabs0 = rt * 32 + c0;
    for (int j = tx; j < nk; j += 16) {
        float a0 = 0.f, a1 = 0.f;
        const float* krow = bufA + j * 64;
        const int sw = j & 15;
        #pragma unroll
        for (int cg = 0; cg < 16; ++cg) {
            float4 k4 = *(const float4*)(krow + ((cg ^ sw) << 2));
            float4 qa = *(const float4*)(qS + c0 * 68 + cg * 4);
            float4 qb = *(const float4*)(qS + (c0 + 1) * 68 + cg * 4);
            a0 += qa.x * k4.x + qa.y * k4.y + qa.z * k4.z + qa.w * k4.w;
            a1 += qb.x * k4.x + qb.y * k4.y + qb.z * k4.z + qb.w * k4.w;
        }
        sS[c0 * 132 + j]       = (j <= cabs0)     ? a0 : 0.f;
        sS[(c0 + 1) * 132 + j] = (j <= cabs0 + 1) ? a1 : 0.f;
    }
    __syncthreads();

    // ---- z (32 threads) while everyone stages kv_prev over the k buffer ----
    if (tid < 32) {
        const int c = tid;
        float z = EPS_;
        #pragma unroll 8
        for (int d = 0; d < 64; ++d) z += qS[c * 68 + d] * kpS[d];
        for (int j = 0; j < nk; ++j) z += sS[c * 132 + j];
        zS[c] = z;
    }
    {
        const float* kvp = kvbuf + stateoff * (Dd * Mm);
        for (int i = tid; i < 1024; i += 256)
            *(float4*)(bufA + i * 4) = *(const float4*)(kvp + i * 4);
    }
    __syncthreads();

    // ---- inter: acc += q . kv_prev ----
    const int m0 = tx * 4;
    float aA0=0,aA1=0,aA2=0,aA3=0, aB0=0,aB1=0,aB2=0,aB3=0;
    #pragma unroll 4
    for (int d = 0; d < 64; ++d) {
        const float q0 = qS[c0 * 68 + d];
        const float q1 = qS[(c0 + 1) * 68 + d];
        float4 kv4 = *(const float4*)(bufA + d * 64 + m0);
        aA0 += q0 * kv4.x; aA1 += q0 * kv4.y; aA2 += q0 * kv4.z; aA3 += q0 * kv4.w;
        aB0 += q1 * kv4.x; aB1 += q1 * kv4.y; aB2 += q1 * kv4.z; aB3 += q1 * kv4.w;
    }
    __syncthreads();

    // ---- stage v over kv_prev ----
    for (int i = tid; i < nk * 16; i += 256) {
        const int j = i >> 4, cg = i & 15;
        *(float4*)(bufA + j * 64 + cg * 4) =
            *(const float4*)(values + chunkbase + (size_t)j * ROWS + cg * 4);
    }
    __syncthreads();

    // ---- intra: acc += s . v (causal) ----
    for (int j = 0; j <= cabs0; ++j) {
        const float s0 = sS[c0 * 132 + j];
        const float s1 = sS[(c0 + 1) * 132 + j];
        float4 v4 = *(const float4*)(bufA + j * 64 + m0);
        aA0 += s0 * v4.x; aA1 += s0 * v4.y; aA2 += s0 * v4.z; aA3 += s0 * v4.w;
        aB0 += s1 * v4.x; aB1 += s1 * v4.y; aB2 += s1 * v4.z; aB3 += s1 * v4.w;
    }
    {   // diagonal term for row c0+1
        const int j = cabs0 + 1;
        const float s1 = sS[(c0 + 1) * 132 + j];
        float4 v4 = *(const float4*)(bufA + j * 64 + m0);
        aB0 += s1 * v4.x; aB1 += s1 * v4.y; aB2 += s1 * v4.z; aB3 += s1 * v4.w;
    }

    const float iz0 = 1.0f / zS[c0], iz1 = 1.0f / zS[c0 + 1];
    const size_t outbase = ((size_t)(n * Ll + g * Cc + rt * 32) * Hh + h) * Mm;
    float4 o0 = make_float4(aA0 * iz0, aA1 * iz0, aA2 * iz0, aA3 * iz0);
    float4 o1 = make_float4(aB0 * iz1, aB1 * iz1, aB2 * iz1, aB3 * iz1);
    *(float4*)(out + outbase + (size_t)c0       * ROWS + m0) = o0;
    *(float4*)(out + outbase + (size_t)(c0 + 1) * ROWS + m0) = o1;
}

extern "C" void kernel_launch(void* const* d_in, const int* in_sizes, int n_in,
                              void* d_out, int out_size, void* d_ws, size_t ws_size,
                              hipStream_t stream) {
    const float* q = (const float*)d_in[0];
    const float* k = (const float*)d_in[1];
    const float* v = (const float*)d_in[2];
    float* out = (float*)d_out;

    // workspace: kv chunk states (33.5 MB) + ksum chunk states (0.5 MB)
    float* kvbuf   = (float*)d_ws;
    float* ksumbuf = kvbuf + (size_t)Nn * Gg * Hh * Dd * Mm;

    kv_state_kernel<<<Nn * Gg * Hh, 256, 0, stream>>>(k, v, kvbuf, ksumbuf);

    const int nseries = Nn * Hh * Dd * Mm + Nn * Hh * Dd;  // 266240
    prefix_kernel<<<nseries / 256, 256, 0, stream>>>(kvbuf, ksumbuf);

    out_kernel<<<Nn * Gg * Hh * 4, 256, 0, stream>>>(q, k, v, kvbuf, ksumbuf, out);
}